// Round 1
// 998.534 us; speedup vs baseline: 1.0136x; 1.0136x over previous
//
#include <hip/hip_runtime.h>
#include <math.h>

#define D 256
#define LDS_STRIDE 40   // 32 + 8 pad shorts: 80B row stride, 16B-aligned, kills 8-way LDS conflicts

typedef __attribute__((ext_vector_type(8))) short short8;
typedef __attribute__((ext_vector_type(4))) float f32x4;

__device__ inline unsigned short f2bf(float f) {
    unsigned int u = __float_as_uint(f);
    u += 0x7fff + ((u >> 16) & 1);          // RNE
    return (unsigned short)(u >> 16);
}
__device__ inline float bf2f(unsigned short h) {
    return __uint_as_float(((unsigned int)h) << 16);
}

// ---------------------------------------------------------------------------
// Fused prep: prev fp32->bf16, Wk fp32->bf16, Wg transpose->bf16, zero counts.
// Block ranges: [0,gPrev) prev cvt | [gPrev,+gWk) Wk cvt | [..,+512) WgT | rest counts.
__global__ __launch_bounds__(256)
void k_prep(const float* __restrict__ prev, const float* __restrict__ Wk,
            const float* __restrict__ Wg,
            unsigned short* __restrict__ prev_bf, unsigned short* __restrict__ Wk_bf,
            unsigned short* __restrict__ WgT, int* __restrict__ counts,
            int n8, int nWk8, int Nn, int gPrev, int gWk, int gWgT) {
    int b = blockIdx.x;
    int t = threadIdx.x;
    if (b < gPrev) {
        int i = b * 256 + t;
        if (i < n8) {
            const float4* p = (const float4*)(prev + (size_t)i * 8);
            float4 a = p[0], c = p[1];
            ushort4 o0 = { f2bf(a.x), f2bf(a.y), f2bf(a.z), f2bf(a.w) };
            ushort4 o1 = { f2bf(c.x), f2bf(c.y), f2bf(c.z), f2bf(c.w) };
            ushort4* q = (ushort4*)(prev_bf + (size_t)i * 8);
            q[0] = o0; q[1] = o1;
        }
    } else if (b < gPrev + gWk) {
        int i = (b - gPrev) * 256 + t;
        if (i < nWk8) {
            const float4* p = (const float4*)(Wk + (size_t)i * 8);
            float4 a = p[0], c = p[1];
            ushort4 o0 = { f2bf(a.x), f2bf(a.y), f2bf(a.z), f2bf(a.w) };
            ushort4 o1 = { f2bf(c.x), f2bf(c.y), f2bf(c.z), f2bf(c.w) };
            ushort4* q = (ushort4*)(Wk_bf + (size_t)i * 8);
            q[0] = o0; q[1] = o1;
        }
    } else if (b < gPrev + gWk + gWgT) {
        int r = b - gPrev - gWk;           // 0..2D-1 (k index)
        int c = t;                          // 0..D-1  (n index)
        WgT[(size_t)c * (2 * D) + r] = f2bf(Wg[(size_t)r * D + c]);
    } else {
        int i = (b - gPrev - gWk - gWgT) * 256 + t;
        if (i < Nn) counts[i] = 0;
    }
}

// ---------------------------------------------------------------------------
// MFMA GEMM: C[M][256] = A[M][K] @ B[K][256], A bf16 (A0 | A1 halves for gate),
// B staged n-major: Bn[n][k]. Block: 64 rows x 256 cols, 4 waves, K-step 32.
// GATE=false: store bf16 wq. GATE=true: gate epilogue -> fp32 out.
template <int K, bool GATE>
__global__ __launch_bounds__(256)
void k_mfma_gemm(const unsigned short* __restrict__ A0,
                 const unsigned short* __restrict__ A1,
                 const unsigned short* __restrict__ Bn,
                 const float* __restrict__ bg,
                 const float* __restrict__ prevf,
                 unsigned short* __restrict__ wq_out,
                 float* __restrict__ outp,
                 int Nrows) {
    __shared__ unsigned short As[64 * LDS_STRIDE];    // 5 KB
    __shared__ unsigned short Bs[256 * LDS_STRIDE];   // 20.5 KB

    int tid  = threadIdx.x;
    int wave = tid >> 6;
    int lane = tid & 63;
    int lcol = lane & 15;
    int quad = lane >> 4;
    int row0 = blockIdx.x * 64;

    f32x4 acc[4][4];
    #pragma unroll
    for (int i = 0; i < 4; i++)
        #pragma unroll
        for (int j = 0; j < 4; j++) acc[i][j] = (f32x4){0.f, 0.f, 0.f, 0.f};

    int arow = tid >> 2, ako = (tid & 3) * 8;
    int grow = row0 + arow;

    for (int kk = 0; kk < K; kk += 32) {
        const unsigned short* Asrc = A0;
        int kc = kk;
        if (GATE && kk >= 256) { Asrc = A1; kc = kk - 256; }

        uint4 av = make_uint4(0u, 0u, 0u, 0u);
        if (grow < Nrows) av = *(const uint4*)&Asrc[(size_t)grow * D + kc + ako];
        *(uint4*)&As[arow * LDS_STRIDE + ako] = av;

        #pragma unroll
        for (int i = 0; i < 4; i++) {
            int c = tid + i * 256;
            int brow = c >> 2, bko = (c & 3) * 8;
            *(uint4*)&Bs[brow * LDS_STRIDE + bko] =
                *(const uint4*)&Bn[(size_t)brow * K + kk + bko];
        }
        __syncthreads();

        short8 a[4], b[4];
        #pragma unroll
        for (int mf = 0; mf < 4; mf++)
            a[mf] = *(const short8*)&As[(mf * 16 + lcol) * LDS_STRIDE + quad * 8];
        #pragma unroll
        for (int nf = 0; nf < 4; nf++)
            b[nf] = *(const short8*)&Bs[(wave * 64 + nf * 16 + lcol) * LDS_STRIDE + quad * 8];
        #pragma unroll
        for (int mf = 0; mf < 4; mf++)
            #pragma unroll
            for (int nf = 0; nf < 4; nf++)
                acc[mf][nf] = __builtin_amdgcn_mfma_f32_16x16x32_bf16(
                    a[mf], b[nf], acc[mf][nf], 0, 0, 0);
        __syncthreads();
    }

    if (!GATE) {
        #pragma unroll
        for (int mf = 0; mf < 4; mf++) {
            #pragma unroll
            for (int nf = 0; nf < 4; nf++) {
                int col = wave * 64 + nf * 16 + lcol;
                #pragma unroll
                for (int r = 0; r < 4; r++) {
                    int gr = row0 + mf * 16 + quad * 4 + r;
                    if (gr < Nrows)
                        wq_out[(size_t)gr * D + col] = f2bf(acc[mf][nf][r]);
                }
            }
        }
    } else {
        float bgv[4];
        #pragma unroll
        for (int nf = 0; nf < 4; nf++) bgv[nf] = bg[wave * 64 + nf * 16 + lcol];
        #pragma unroll
        for (int mf = 0; mf < 4; mf++) {
            #pragma unroll
            for (int nf = 0; nf < 4; nf++) {
                int col = wave * 64 + nf * 16 + lcol;
                #pragma unroll
                for (int r = 0; r < 4; r++) {
                    int gr = row0 + mf * 16 + quad * 4 + r;
                    if (gr < Nrows) {
                        size_t o = (size_t)gr * D + col;
                        float logit = acc[mf][nf][r] + bgv[nf];
                        float g = 1.f / (1.f + __expf(-logit));
                        float cb = bf2f(A1[o]);
                        outp[o] = g * prevf[o] + (1.f - g) * cb;
                    }
                }
            }
        }
    }
}

// ---------------------------------------------------------------------------
// Counting sort of occurrence ids by node index.
__global__ __launch_bounds__(256)
void k_hist(const int* __restrict__ idx, int* __restrict__ counts,
            int* __restrict__ rank, int E_) {
    int e = blockIdx.x * 256 + threadIdx.x;
    if (e < E_) rank[e] = atomicAdd(&counts[idx[e]], 1);
}

__global__ __launch_bounds__(256)
void k_part(const int* __restrict__ counts, int* __restrict__ chunkSums, int Nn) {
    __shared__ int sd[256];
    int base = blockIdx.x * 1024;
    int t = threadIdx.x;
    int s = 0;
    #pragma unroll
    for (int i = 0; i < 4; i++) {
        int g = base + t + i * 256;
        if (g < Nn) s += counts[g];
    }
    sd[t] = s;
    __syncthreads();
    for (int st = 128; st; st >>= 1) {
        if (t < st) sd[t] += sd[t + st];
        __syncthreads();
    }
    if (t == 0) chunkSums[blockIdx.x] = sd[0];
}

__global__ __launch_bounds__(256)
void k_top(const int* __restrict__ cs, int* __restrict__ co, int P,
           int* __restrict__ offsets, int Nn, int E_) {
    __shared__ int carry;
    __shared__ int ws[4];
    int t = threadIdx.x, lane = t & 63, w = t >> 6;
    if (t == 0) carry = 0;
    __syncthreads();
    for (int base = 0; base < P; base += 256) {
        int i = base + t;
        int v = (i < P) ? cs[i] : 0;
        int orig = v;
        for (int off = 1; off < 64; off <<= 1) {
            int u = __shfl_up(v, off, 64);
            if (lane >= off) v += u;
        }
        if (lane == 63) ws[w] = v;
        __syncthreads();
        int wex = 0;
        for (int k = 0; k < w; k++) wex += ws[k];
        int incl = v + wex;
        if (i < P) co[i] = carry + incl - orig;
        __syncthreads();
        if (t == 255) carry += incl;
        __syncthreads();
    }
    if (t == 0) offsets[Nn] = E_;
}

__global__ __launch_bounds__(256)
void k_off(const int* __restrict__ counts, const int* __restrict__ chunkOff,
           int* __restrict__ offsets, int Nn) {
    int t = threadIdx.x, lane = t & 63, w = t >> 6;
    int base = blockIdx.x * 1024 + t * 4;
    int c[4]; int ts = 0;
    #pragma unroll
    for (int j = 0; j < 4; j++) {
        int g = base + j;
        c[j] = (g < Nn) ? counts[g] : 0;
        ts += c[j];
    }
    int v = ts;
    for (int off = 1; off < 64; off <<= 1) {
        int u = __shfl_up(v, off, 64);
        if (lane >= off) v += u;
    }
    __shared__ int ws[4];
    if (lane == 63) ws[w] = v;
    __syncthreads();
    int wex = 0;
    for (int k = 0; k < w; k++) wex += ws[k];
    int run = chunkOff[blockIdx.x] + wex + v - ts;
    #pragma unroll
    for (int j = 0; j < 4; j++) {
        int g = base + j;
        if (g < Nn) offsets[g] = run;
        run += c[j];
    }
}

__global__ __launch_bounds__(256)
void k_scatter(const int* __restrict__ idx, const int* __restrict__ rank,
               const int* __restrict__ offsets, int* __restrict__ perm, int E_) {
    int e = blockIdx.x * 256 + threadIdx.x;
    if (e < E_) perm[offsets[idx[e]] + rank[e]] = e;
}

// ---------------------------------------------------------------------------
// One wave per node: online-softmax attention; 2-deep row prefetch to cover
// HBM latency across the reduce/exp chain. wq in bf16 (L3-resident gather).
__global__ __launch_bounds__(256)
void k_combine(const float* __restrict__ scat, const unsigned short* __restrict__ wq,
               const int* __restrict__ offsets, const int* __restrict__ perm,
               unsigned short* __restrict__ comb, int Nnodes) {
    int wave = threadIdx.x >> 6;
    int lane = threadIdx.x & 63;
    int n = blockIdx.x * 4 + wave;
    if (n >= Nnodes) return;

    ushort4 wu = *(const ushort4*)&wq[(size_t)n * D + lane * 4];
    float4 wqv = { bf2f(wu.x), bf2f(wu.y), bf2f(wu.z), bf2f(wu.w) };
    int beg = offsets[n], end = offsets[n + 1];

    float m = -INFINITY, l = 0.f;
    float4 acc = { 0.f, 0.f, 0.f, 0.f };
    const float scale = 0.0625f;   // 1/sqrt(256)

    if (beg < end) {
        int e0 = perm[beg];
        float4 sv0 = *(const float4*)&scat[(size_t)e0 * D + lane * 4];
        float4 sv1 = sv0;
        if (beg + 1 < end) {
            int e1 = perm[beg + 1];
            sv1 = *(const float4*)&scat[(size_t)e1 * D + lane * 4];
        }
        for (int pos = beg; pos < end; ++pos) {
            float4 cur = sv0;
            sv0 = sv1;
            if (pos + 2 < end) {
                int e2 = perm[pos + 2];
                sv1 = *(const float4*)&scat[(size_t)e2 * D + lane * 4];
            }
            float d = fmaf(cur.x, wqv.x, fmaf(cur.y, wqv.y,
                      fmaf(cur.z, wqv.z, cur.w * wqv.w)));
            #pragma unroll
            for (int off = 32; off; off >>= 1) d += __shfl_xor(d, off, 64);
            float score = d * scale;
            float nm = fmaxf(m, score);
            float al = __expf(m - nm);       // first iter: exp(-inf)=0
            float p  = __expf(score - nm);
            l = fmaf(l, al, p);
            acc.x = fmaf(acc.x, al, p * cur.x);
            acc.y = fmaf(acc.y, al, p * cur.y);
            acc.z = fmaf(acc.z, al, p * cur.z);
            acc.w = fmaf(acc.w, al, p * cur.w);
            m = nm;
        }
    }
    float inv = 1.f / fmaxf(l, 1e-9f);
    ushort4 o = { f2bf(acc.x * inv), f2bf(acc.y * inv),
                  f2bf(acc.z * inv), f2bf(acc.w * inv) };
    *(ushort4*)&comb[(size_t)n * D + lane * 4] = o;
}

// ---------------------------------------------------------------------------
extern "C" void kernel_launch(void* const* d_in, const int* in_sizes, int n_in,
                              void* d_out, int out_size, void* d_ws, size_t ws_size,
                              hipStream_t stream) {
    const float* scat = (const float*)d_in[0];
    const float* prev = (const float*)d_in[1];
    const float* Wk   = (const float*)d_in[2];
    // d_in[3] = b_k: constant shift within a segment cancels in softmax.
    const float* Wg   = (const float*)d_in[4];
    const float* bg   = (const float*)d_in[5];
    const int*   idx  = (const int*)d_in[6];

    const int E_ = in_sizes[6];
    const int Nn = in_sizes[1] / D;

    float* out = (float*)d_out;

    char* w = (char*)d_ws;
    auto alloc = [&](size_t bytes) -> char* {
        char* p = w;
        w += (bytes + 255) & ~(size_t)255;
        return p;
    };
    unsigned short* prev_bf = (unsigned short*)alloc((size_t)Nn * D * 2);
    unsigned short* wq_bf   = (unsigned short*)alloc((size_t)Nn * D * 2);
    unsigned short* comb_bf = (unsigned short*)alloc((size_t)Nn * D * 2);
    unsigned short* Wk_bf   = (unsigned short*)alloc((size_t)D * D * 2);
    unsigned short* WgT_bf  = (unsigned short*)alloc((size_t)2 * D * D * 2);
    int*   counts    = (int*)alloc((size_t)Nn * 4);
    int*   offsets   = (int*)alloc(((size_t)Nn + 1) * 4);
    int    P         = (Nn + 1023) / 1024;
    int*   chunkSums = (int*)alloc((size_t)P * 4);
    int*   chunkOff  = (int*)alloc((size_t)P * 4);
    int*   rank      = (int*)alloc((size_t)E_ * 4);
    int*   perm      = (int*)alloc((size_t)E_ * 4);

    // 1) fused conversions + counts zero (one launch)
    int n8    = Nn * D / 8;
    int nWk8  = D * D / 8;
    int gPrev = (n8 + 255) / 256;
    int gWk   = (nWk8 + 255) / 256;
    int gWgT  = 2 * D;
    int gCnt  = (Nn + 255) / 256;
    k_prep<<<gPrev + gWk + gWgT + gCnt, 256, 0, stream>>>(
        prev, Wk, Wg, prev_bf, Wk_bf, WgT_bf, counts,
        n8, nWk8, Nn, gPrev, gWk, gWgT);

    // 2) counting sort of occurrences by node
    int gb = (E_ + 255) / 256;
    k_hist<<<gb, 256, 0, stream>>>(idx, counts, rank, E_);
    k_part<<<P, 256, 0, stream>>>(counts, chunkSums, Nn);
    k_top<<<1, 256, 0, stream>>>(chunkSums, chunkOff, P, offsets, Nn, E_);
    k_off<<<P, 256, 0, stream>>>(counts, chunkOff, offsets, Nn);
    k_scatter<<<gb, 256, 0, stream>>>(idx, rank, offsets, perm, E_);

    // 3) wq = prev @ Wk^T  (MFMA; Wk row-major IS the n-major B)
    int gm = (Nn + 63) / 64;
    k_mfma_gemm<256, false><<<gm, 256, 0, stream>>>(
        prev_bf, nullptr, Wk_bf, nullptr, nullptr, wq_bf, nullptr, Nn);

    // 4) per-node online-softmax attention (single pass over scattered_input)
    k_combine<<<(Nn + 3) / 4, 256, 0, stream>>>(scat, wq_bf, offsets, perm, comb_bf, Nn);

    // 5) gate GEMM + sigmoid lerp epilogue (MFMA)
    k_mfma_gemm<512, true><<<gm, 256, 0, stream>>>(
        prev_bf, comb_bf, WgT_bf, bg, prev, nullptr, out, Nn);
}